// Round 3
// baseline (793.697 us; speedup 1.0000x reference)
//
#include <hip/hip_runtime.h>
#include <hip/hip_bf16.h>
#include <math.h>

// CnnLstmCrf on MI355X, fp32-exact. Round 2: remove ALL readlane machinery;
// serial kernels (lstm, viterbi) use plain LDS broadcast + barriers.
// Sizes: B=64 S=250 CL=16 CV=100 CD=300 CH=50 WD=300 FD=5
// IN=355 H=100 4H=400 HD=200 T=22 START=20 STOP=21
//
// Workspace layout (floats). lstm_out/feats alias the wrep region (dead after gemm).
#define WS_U        0          // 15000 -> pad 15360
#define WS_WPAD     15360      // 896*384 = 344064
#define WS_WREP     359424     // 16000*384 = 6144000 (reused below)
#define WS_PRE      6503424    // 16000*800 = 12800000 (end 19303424 floats = 77.2MB)
#define WS_LSTM     359424     // alias wrep: 16000*200 = 3200000 (< 6144000)
#define WS_FEATS    3559424    // alias wrep tail: 16000*22 = 352000 (ends 3911424)

// ---------------- prep: pad w_ih into [896][384] ----------------
__global__ __launch_bounds__(256) void prepw_kernel(
    const float* __restrict__ wf, const float* __restrict__ wb,
    float* __restrict__ w_pad) {
  int idx = blockIdx.x * 256 + threadIdx.x;
  if (idx >= 896 * 384) return;
  int col = idx % 384, row = idx / 384;
  float v = 0.f;
  if (col < 355) {
    if (row < 400)      v = wf[row * 355 + col];
    else if (row < 800) v = wb[(row - 400) * 355 + col];
  }
  w_pad[idx] = v;
}

// ---------------- U table: U[(c*3+k)*50+o] ----------------
__global__ __launch_bounds__(256) void u_kernel(
    const float* __restrict__ char_emb, const float* __restrict__ conv_w,
    float* __restrict__ U) {
  int idx = blockIdx.x * 256 + threadIdx.x;
  if (idx >= 15000) return;
  int c = idx / 150, rem = idx % 150, k = rem / 50, o = rem % 50;
  float acc = 0.f;
  for (int i = 0; i < 300; i++)
    acc += char_emb[c * 300 + i] * conv_w[(o * 300 + i) * 3 + k];
  U[idx] = acc;
}

// ---------------- assemble word_rep rows ----------------
__global__ __launch_bounds__(64) void assemble_kernel(
    const int* __restrict__ batch_word, const int* __restrict__ batch_feats,
    const int* __restrict__ batch_char, const int* __restrict__ recover,
    const float* __restrict__ word_emb, const float* __restrict__ feat_emb,
    const float* __restrict__ conv_b, const float* __restrict__ U,
    float* __restrict__ wrep) {
  int n = blockIdx.x;
  int tid = threadIdx.x;
  __shared__ int ch[16];
  if (tid < 16) ch[tid] = batch_char[(size_t)recover[n] * 16 + tid];
  __syncthreads();
  float* dst = wrep + (size_t)n * 384;
  int w = batch_word[n];
  for (int i = tid; i < 300; i += 64) dst[i] = word_emb[(size_t)w * 300 + i];
  if (tid < 34) {  // feat_emb (5) + zero pad (29)
    int i = 350 + tid;
    dst[i] = (i < 355) ? feat_emb[batch_feats[n] * 5 + (i - 350)] : 0.f;
  }
  if (tid < 50) {  // char CNN via U table, max over 16 positions
    int o = tid;
    float bo = conv_b[o];
    float m = -1e30f;
#pragma unroll
    for (int l = 0; l < 16; l++) {
      float v = bo + U[(ch[l] * 3 + 1) * 50 + o];
      if (l > 0)  v += U[(ch[l - 1] * 3 + 0) * 50 + o];
      if (l < 15) v += U[(ch[l + 1] * 3 + 2) * 50 + o];
      m = fmaxf(m, v);
    }
    dst[300 + o] = m;
  }
}

// ---------------- fp32 GEMM: C[16000][800] = A[16000][384] @ B[896][384]^T + bias
__global__ __launch_bounds__(256, 4) void gemm_kernel(
    const float* __restrict__ A, const float* __restrict__ B,
    float* __restrict__ C, const float* __restrict__ bf,
    const float* __restrict__ bb) {
  __shared__ float As[16][128];
  __shared__ float Bs[16][128];
  int tid = threadIdx.x;
  int m0 = blockIdx.x * 128;
  int n0 = blockIdx.y * 128;
  int tx = tid & 15, ty = tid >> 4;
  int lr = tid >> 2;
  int lc = (tid & 3) * 4;
  float acc[8][8];
#pragma unroll
  for (int i = 0; i < 8; i++)
#pragma unroll
    for (int j = 0; j < 8; j++) acc[i][j] = 0.f;

  for (int k0 = 0; k0 < 384; k0 += 16) {
#pragma unroll
    for (int h = 0; h < 2; h++) {
      int row = lr + h * 64;
      float4 av = *(const float4*)(A + (size_t)(m0 + row) * 384 + k0 + lc);
      As[lc + 0][row] = av.x; As[lc + 1][row] = av.y;
      As[lc + 2][row] = av.z; As[lc + 3][row] = av.w;
      float4 bv = *(const float4*)(B + (size_t)(n0 + row) * 384 + k0 + lc);
      Bs[lc + 0][row] = bv.x; Bs[lc + 1][row] = bv.y;
      Bs[lc + 2][row] = bv.z; Bs[lc + 3][row] = bv.w;
    }
    __syncthreads();
#pragma unroll
    for (int k = 0; k < 16; k++) {
      float a[8], b[8];
      *(float4*)&a[0] = *(const float4*)&As[k][ty * 8];
      *(float4*)&a[4] = *(const float4*)&As[k][ty * 8 + 4];
      *(float4*)&b[0] = *(const float4*)&Bs[k][tx * 8];
      *(float4*)&b[4] = *(const float4*)&Bs[k][tx * 8 + 4];
#pragma unroll
      for (int i = 0; i < 8; i++)
#pragma unroll
        for (int j = 0; j < 8; j++) acc[i][j] += a[i] * b[j];
    }
    __syncthreads();
  }
#pragma unroll
  for (int i = 0; i < 8; i++) {
    int m = m0 + ty * 8 + i;
#pragma unroll
    for (int jj = 0; jj < 8; jj++) {
      int j = n0 + tx * 8 + jj;
      if (j < 800) {
        float bias = (j < 400) ? bf[j] : bb[j - 400];
        C[(size_t)m * 800 + j] = acc[i][jj] + bias;
      }
    }
  }
}

// ---------------- BiLSTM scan: 128 blocks = (dir, row) ----------------
// BORING version: h lives in LDS; each gate thread reads h via ds_read
// (same-address broadcast, no conflicts). No readlane anywhere.
__global__ __launch_bounds__(256, 2) void lstm_kernel(
    const float* __restrict__ pre, const float* __restrict__ w_hh_f,
    const float* __restrict__ w_hh_b, const int* __restrict__ wordlen,
    float* __restrict__ lstm_out) {
  int tid = threadIdx.x;
  int dir = blockIdx.x >> 6;
  int r = blockIdx.x & 63;
  int len = wordlen[r];
  const float* __restrict__ Wh = dir ? w_hh_b : w_hh_f;
  __shared__ float h_sh[128];
  __shared__ float g_sh[400];
  float W1[100], W2[100];
  int j1 = tid, j2 = tid + 200;
  if (tid < 200) {
    const float4* w1 = (const float4*)(Wh + j1 * 100);
    const float4* w2 = (const float4*)(Wh + j2 * 100);
#pragma unroll
    for (int q = 0; q < 25; q++) {
      float4 a = w1[q], b = w2[q];
      W1[4 * q] = a.x; W1[4 * q + 1] = a.y; W1[4 * q + 2] = a.z; W1[4 * q + 3] = a.w;
      W2[4 * q] = b.x; W2[4 * q + 1] = b.y; W2[4 * q + 2] = b.z; W2[4 * q + 3] = b.w;
    }
  }
  if (tid < 128) h_sh[tid] = 0.f;
  float c_reg = 0.f;
  const float* __restrict__ pr = pre + dir * 400;
  int p0 = dir ? 249 : 0;
  int dp = dir ? -1 : 1;
  size_t rowbase = (size_t)r * 250;
  float pv1 = 0.f, pv2 = 0.f;
  if (tid < 200) {
    size_t off = (rowbase + p0) * 800;
    pv1 = pr[off + j1];
    pv2 = pr[off + j2];
  }
  __syncthreads();
  for (int i = 0; i < 250; i++) {
    int p = p0 + dp * i;
    if (tid < 200) {
      float g1 = pv1, g2 = pv2;
      if (i < 249) {  // prefetch next step's input projection
        size_t off = (rowbase + p + dp) * 800;
        pv1 = pr[off + j1];
        pv2 = pr[off + j2];
      }
      // h broadcast from LDS, vectorized; h_sh holds step i-1's h.
#pragma unroll
      for (int q = 0; q < 25; q++) {
        float4 hv = *(const float4*)&h_sh[4 * q];
        g1 += hv.x * W1[4 * q]     + hv.y * W1[4 * q + 1]
            + hv.z * W1[4 * q + 2] + hv.w * W1[4 * q + 3];
        g2 += hv.x * W2[4 * q]     + hv.y * W2[4 * q + 1]
            + hv.z * W2[4 * q + 2] + hv.w * W2[4 * q + 3];
      }
      g_sh[j1] = g1;
      g_sh[j2] = g2;
    }
    __syncthreads();  // A: g_sh complete; h_sh reads of step i done
    if (tid < 100) {
      float gi = g_sh[tid], gf = g_sh[100 + tid];
      float gg = g_sh[200 + tid], go = g_sh[300 + tid];
      float hv;
      if (p < len) {
        float si = 1.f / (1.f + expf(-gi));
        float sf = 1.f / (1.f + expf(-gf));
        float so = 1.f / (1.f + expf(-go));
        c_reg = sf * c_reg + si * tanhf(gg);
        hv = so * tanhf(c_reg);
        h_sh[tid] = hv;
      } else {
        hv = h_sh[tid];  // masked: carry previous h (0 for backward prefix)
      }
      lstm_out[(rowbase + p) * 200 + dir * 100 + tid] = hv;
    }
    __syncthreads();  // B: h_sh update visible before next step's reads
  }
}

// ---------------- projection: feats = lstm_out @ proj_w + proj_b ----------------
__global__ __launch_bounds__(256) void proj_kernel(
    const float* __restrict__ lstm_out, const float* __restrict__ proj_w,
    const float* __restrict__ proj_b, float* __restrict__ feats) {
  __shared__ float L[8][200];
  int tid = threadIdx.x;
  size_t base = (size_t)blockIdx.x * 8 * 200;
  for (int idx = tid; idx < 1600; idx += 256)
    L[idx / 200][idx % 200] = lstm_out[base + idx];
  __syncthreads();
  int ty = tid >> 5, c = tid & 31;
  if (c < 22) {
    float acc = proj_b[c];
#pragma unroll 8
    for (int k = 0; k < 200; k++) acc += L[ty][k] * proj_w[k * 22 + c];
    feats[((size_t)blockIdx.x * 8 + ty) * 22 + c] = acc;
  }
}

// ---------------- Viterbi: one wave per batch row (BORING: LDS delta) ----------
__global__ __launch_bounds__(64) void viterbi_kernel(
    const float* __restrict__ feats, const float* __restrict__ trans,
    const int* __restrict__ wordlen, int* __restrict__ out) {
  int r = blockIdx.x;
  int lane = threadIdx.x;
  __shared__ float dsh[22];          // delta (current)
  __shared__ float tsh[22][23];      // trans[k][c], padded stride 23
  __shared__ unsigned char bps[250][22];
  int len = wordlen[r];
  const float* __restrict__ fr = feats + (size_t)r * 250 * 22;
  for (int idx = lane; idx < 484; idx += 64)
    tsh[idx / 22][idx % 22] = trans[idx];
  if (lane < 22) dsh[lane] = trans[20 * 22 + lane] + fr[lane];  // START row
  __syncthreads();
  for (int t = 1; t < 250; t++) {
    float best = -1e30f, fv = 0.f;
    int arg = 0;
    if (lane < 22) {
      fv = fr[t * 22 + lane];
#pragma unroll
      for (int k = 0; k < 22; k++) {
        float cand = dsh[k] + tsh[k][lane];
        if (cand > best) { best = cand; arg = k; }  // first-max == np.argmax
      }
    }
    __syncthreads();  // all dsh reads complete
    if (lane < 22) {
      bool valid = t < len;
      if (valid) dsh[lane] = best + fv;
      bps[t][lane] = valid ? (unsigned char)arg : (unsigned char)lane;
    }
    __syncthreads();  // dsh writes visible
  }
  if (lane == 0) {
    float best = -1e30f;
    int last = 0;
#pragma unroll
    for (int k = 0; k < 22; k++) {
      float cand = dsh[k] + tsh[k][21];  // + trans[:, STOP]
      if (cand > best) { best = cand; last = k; }
    }
    int tag = last;
    out[r * 250 + 249] = tag;
    for (int t = 249; t >= 1; t--) {
      tag = bps[t][tag];
      out[r * 250 + t - 1] = tag;
    }
  }
}

extern "C" void kernel_launch(void* const* d_in, const int* in_sizes, int n_in,
                              void* d_out, int out_size, void* d_ws, size_t ws_size,
                              hipStream_t stream) {
  const int* batch_word  = (const int*)d_in[0];
  const int* batch_feats = (const int*)d_in[1];
  const int* wordlen     = (const int*)d_in[2];
  const int* batch_char  = (const int*)d_in[3];
  // d_in[4] batch_charlen: unused by reference
  const int* recover     = (const int*)d_in[5];
  // d_in[6] mask: recomputed from wordlen (bool dtype ambiguity)
  const float* char_emb  = (const float*)d_in[7];
  const float* word_emb  = (const float*)d_in[8];
  const float* feat_emb  = (const float*)d_in[9];
  const float* conv_w    = (const float*)d_in[10];
  const float* conv_b    = (const float*)d_in[11];
  const float* w_ih_f    = (const float*)d_in[12];
  const float* w_hh_f    = (const float*)d_in[13];
  const float* b_f       = (const float*)d_in[14];
  const float* w_ih_b    = (const float*)d_in[15];
  const float* w_hh_b    = (const float*)d_in[16];
  const float* b_b       = (const float*)d_in[17];
  const float* proj_w    = (const float*)d_in[18];
  const float* proj_b    = (const float*)d_in[19];
  const float* trans     = (const float*)d_in[20];
  int* out = (int*)d_out;
  float* ws = (float*)d_ws;

  float* U        = ws + WS_U;
  float* w_pad    = ws + WS_WPAD;
  float* wrep     = ws + WS_WREP;
  float* pre      = ws + WS_PRE;
  float* lstm_out = ws + WS_LSTM;   // aliases wrep (dead after gemm)
  float* feats    = ws + WS_FEATS;  // aliases wrep tail

  prepw_kernel<<<1344, 256, 0, stream>>>(w_ih_f, w_ih_b, w_pad);
  u_kernel<<<59, 256, 0, stream>>>(char_emb, conv_w, U);
  assemble_kernel<<<16000, 64, 0, stream>>>(batch_word, batch_feats, batch_char,
                                            recover, word_emb, feat_emb, conv_b,
                                            U, wrep);
  dim3 ggrid(125, 7);
  gemm_kernel<<<ggrid, 256, 0, stream>>>(wrep, w_pad, pre, b_f, b_b);
  lstm_kernel<<<128, 256, 0, stream>>>(pre, w_hh_f, w_hh_b, wordlen, lstm_out);
  proj_kernel<<<2000, 256, 0, stream>>>(lstm_out, proj_w, proj_b, feats);
  viterbi_kernel<<<64, 64, 0, stream>>>(feats, trans, wordlen, out);
}